// Round 1
// 801.696 us; speedup vs baseline: 1.0474x; 1.0474x over previous
//
#include <hip/hip_runtime.h>

// LieNet: h = relu(src@Wm+bm); tmp = relu(cat(h[s],h[s+1])@Wb+bb); out = cumsum_s(h[:-1]+tmp)
// S=2048, B=256, D=128. All fp32 in/out; internal GEMMs in bf16 MFMA (fp32 acc).
//
// Pipeline (this version):
//   k0_prep   : swizzle Wm/Wb into MFMA B-fragment order (bf16)
//   k1_h      : h = relu(src@Wm+bm) -> bf16. Wave = 16 rows x 32 cols, Wm frags reg-cached,
//               8 row-tiles per block (4096 blocks).
//   k2_fused  : per (segment, row-tile) block loops 32 s-values: g[s] = relu(h[s]@Wb0 +
//               h[s+1]@Wb1 + bb) + h[s], writes g (=out) AND accumulates per-segment
//               column sums in registers -> segsum. Wb0 frags reg-cached (loop-invariant).
//   k3_prefix : in-place exclusive prefix over the 64 segment sums per column.
//   k4_apply  : float4 rmw: out[s] = prefix[seg] + running sum within segment.
//
// Workspace layout (~142.7 MB):
//   [0, 134217728)               h as bf16, [S=2048][B=256][D=128]
//   [134217728, 142606336)       segsum fp32, [NSEG=64][32768]
//   [142606336, 142639104)       Wm swizzled bf16 (16384 elems)
//   [142639104, 142704640)       Wb swizzled bf16 (32768 elems, two 128-halves)

#define S_DIM 2048
#define B_DIM 256
#define D_DIM 128
#define SM1   2047
#define NCOL  (B_DIM * D_DIM)   // 32768
#define NSEG  64
#define SEGLEN 32               // 64*32 = 2048 >= 2047

typedef __attribute__((ext_vector_type(8))) short bf16x8;
typedef __attribute__((ext_vector_type(4))) float f32x4;

__device__ inline short f2bf(float x) {
    unsigned u = __builtin_bit_cast(unsigned, x);
    unsigned r = (u + 0x7fffu + ((u >> 16) & 1u)) >> 16;
    return (short)r;
}
__device__ inline float bf2f(short v) {
    unsigned u = ((unsigned)(unsigned short)v) << 16;
    return __builtin_bit_cast(float, u);
}

// ---------------- K0: swizzle weights into MFMA B-fragment order ----------------
// B-fragment for mfma_f32_16x16x32_bf16: lane holds B[k=quad*8+j][n=(lane&15)],
// j=0..7. Swizzled index: ((n_tile*4 + kt)*64 + lane)*8 + j.
__global__ __launch_bounds__(256) void k0_prep(const float* __restrict__ Wm,
                                               const float* __restrict__ Wb,
                                               short* __restrict__ Wm_sw,
                                               short* __restrict__ Wb_sw) {
    int idx = blockIdx.x * 256 + threadIdx.x;
    if (idx < 16384) {
        int j = idx & 7, lane = (idx >> 3) & 63, kt = (idx >> 9) & 3, nt = idx >> 11;
        int k = kt * 32 + ((lane >> 4) << 3) + j;
        int n = nt * 16 + (lane & 15);
        Wm_sw[idx] = f2bf(Wm[k * D_DIM + n]);
    }
    if (idx < 32768) {
        int half = idx >> 14;
        int r = idx & 16383;
        int j = r & 7, lane = (r >> 3) & 63, kt = (r >> 9) & 3, nt = r >> 11;
        int k = kt * 32 + ((lane >> 4) << 3) + j;
        int n = nt * 16 + (lane & 15);
        Wb_sw[idx] = f2bf(Wb[(half * 128 + k) * D_DIM + n]);
    }
}

// ---------------- K1: h = relu(src @ Wm + bm), bf16 out ----------------
// Block = 4 waves, wave w owns cols [w*32, w*32+32). 8 row-tiles of 16 rows per block.
// Wm B-fragments (8 per wave) are register-resident for the whole block.
#define K1_RT 8
__global__ __launch_bounds__(256, 4) void k1_h(const float* __restrict__ src,
                                               const short* __restrict__ Wm_sw,
                                               const float* __restrict__ bm,
                                               short* __restrict__ h) {
    const int lane = threadIdx.x & 63;
    const int wave = threadIdx.x >> 6;
    const int m = lane & 15;
    const int quad = lane >> 4;
    const int wbase = wave * 32;
    const int n0 = wave * 2;

    bf16x8 bw[2][4];
#pragma unroll
    for (int n = 0; n < 2; ++n)
#pragma unroll
        for (int kt = 0; kt < 4; ++kt)
            bw[n][kt] = *(const bf16x8*)(Wm_sw + ((size_t)((n0 + n) * 4 + kt) * 64 + lane) * 8);

    const float bias0 = bm[wbase + m];
    const float bias1 = bm[wbase + 16 + m];

#pragma unroll 1
    for (int r = 0; r < K1_RT; ++r) {
        const int rowBase = blockIdx.x * (16 * K1_RT) + r * 16;
        const float* arow = src + (size_t)(rowBase + m) * D_DIM + quad * 8;

        bf16x8 a[4];
#pragma unroll
        for (int kt = 0; kt < 4; ++kt) {
            float4 lo = *(const float4*)(arow + kt * 32);
            float4 hi = *(const float4*)(arow + kt * 32 + 4);
            a[kt][0] = f2bf(lo.x); a[kt][1] = f2bf(lo.y);
            a[kt][2] = f2bf(lo.z); a[kt][3] = f2bf(lo.w);
            a[kt][4] = f2bf(hi.x); a[kt][5] = f2bf(hi.y);
            a[kt][6] = f2bf(hi.z); a[kt][7] = f2bf(hi.w);
        }

        f32x4 acc0 = (f32x4){0.f, 0.f, 0.f, 0.f};
        f32x4 acc1 = (f32x4){0.f, 0.f, 0.f, 0.f};
#pragma unroll
        for (int kt = 0; kt < 4; ++kt) {
            acc0 = __builtin_amdgcn_mfma_f32_16x16x32_bf16(a[kt], bw[0][kt], acc0, 0, 0, 0);
            acc1 = __builtin_amdgcn_mfma_f32_16x16x32_bf16(a[kt], bw[1][kt], acc1, 0, 0, 0);
        }

        // C/D layout: col = lane&15, row = quad*4 + i
        short* hout = h + (size_t)(rowBase + quad * 4) * D_DIM;
#pragma unroll
        for (int i = 0; i < 4; ++i) {
            float v0 = acc0[i] + bias0;
            v0 = v0 > 0.f ? v0 : 0.f;
            hout[(size_t)i * D_DIM + wbase + m] = f2bf(v0);
            float v1 = acc1[i] + bias1;
            v1 = v1 > 0.f ? v1 : 0.f;
            hout[(size_t)i * D_DIM + wbase + 16 + m] = f2bf(v1);
        }
    }
}

// ---------------- K2: fused g-compute + per-segment column sums ----------------
// Grid = NSEG * 16 row-tiles. Block = 4 waves, wave w owns cols [w*32, w*32+32),
// block owns rows [rt*16, rt*16+16) of all s in its segment.
// g[s] = relu(h[s]@Wb0 + h[s+1]@Wb1 + bb) + h[s]; segacc += g[s].
__global__ __launch_bounds__(256, 4) void k2_fused(const short* __restrict__ h,
                                                   const short* __restrict__ Wb_sw,
                                                   const float* __restrict__ bb,
                                                   float* __restrict__ g,
                                                   float* __restrict__ segsum) {
    const int lane = threadIdx.x & 63;
    const int wave = threadIdx.x >> 6;
    const int m = lane & 15;
    const int quad = lane >> 4;
    const int seg = blockIdx.x >> 4;
    const int rB = (blockIdx.x & 15) * 16;
    const int wbase = wave * 32;
    const int n0 = wave * 2;

    // Wb half-0 fragments: register-resident across the whole segment loop.
    bf16x8 bw0[2][4];
#pragma unroll
    for (int n = 0; n < 2; ++n)
#pragma unroll
        for (int kt = 0; kt < 4; ++kt)
            bw0[n][kt] = *(const bf16x8*)(Wb_sw + ((size_t)((n0 + n) * 4 + kt) * 64 + lane) * 8);
    const short* wb1 = Wb_sw + 16384;   // half-1 stays in L1/L2 (32 KB)

    const float bias0 = bb[wbase + m];
    const float bias1 = bb[wbase + 16 + m];

    f32x4 sa0 = (f32x4){0.f, 0.f, 0.f, 0.f};
    f32x4 sa1 = (f32x4){0.f, 0.f, 0.f, 0.f};

    const int s0 = seg * SEGLEN;
    const int send = min(s0 + SEGLEN, SM1);

#pragma unroll 1
    for (int s = s0; s < send; ++s) {
        const short* h0 = h + ((size_t)s * B_DIM + rB + m) * D_DIM + quad * 8;

        bf16x8 a[4];
#pragma unroll
        for (int kt = 0; kt < 4; ++kt) a[kt] = *(const bf16x8*)(h0 + kt * 32);

        f32x4 acc0 = (f32x4){0.f, 0.f, 0.f, 0.f};
        f32x4 acc1 = (f32x4){0.f, 0.f, 0.f, 0.f};
#pragma unroll
        for (int kt = 0; kt < 4; ++kt) {
            acc0 = __builtin_amdgcn_mfma_f32_16x16x32_bf16(a[kt], bw0[0][kt], acc0, 0, 0, 0);
            acc1 = __builtin_amdgcn_mfma_f32_16x16x32_bf16(a[kt], bw0[1][kt], acc1, 0, 0, 0);
        }

        const short* h1 = h0 + (size_t)B_DIM * D_DIM;
#pragma unroll
        for (int kt = 0; kt < 4; ++kt) a[kt] = *(const bf16x8*)(h1 + kt * 32);
#pragma unroll
        for (int kt = 0; kt < 4; ++kt) {
            bf16x8 b0 = *(const bf16x8*)(wb1 + ((size_t)(n0 * 4 + kt) * 64 + lane) * 8);
            acc0 = __builtin_amdgcn_mfma_f32_16x16x32_bf16(a[kt], b0, acc0, 0, 0, 0);
            bf16x8 b1 = *(const bf16x8*)(wb1 + ((size_t)((n0 + 1) * 4 + kt) * 64 + lane) * 8);
            acc1 = __builtin_amdgcn_mfma_f32_16x16x32_bf16(a[kt], b1, acc1, 0, 0, 0);
        }

        // epilogue: bias, relu, +h residual, store g, accumulate segment sum
        const short* hr = h + ((size_t)s * B_DIM + rB + quad * 4) * D_DIM;
        float* gr = g + ((size_t)s * NCOL + (size_t)(rB + quad * 4) * D_DIM);
#pragma unroll
        for (int i = 0; i < 4; ++i) {
            float v0 = acc0[i] + bias0;
            v0 = v0 > 0.f ? v0 : 0.f;
            v0 += bf2f(hr[(size_t)i * D_DIM + wbase + m]);
            gr[(size_t)i * D_DIM + wbase + m] = v0;
            sa0[i] += v0;

            float v1 = acc1[i] + bias1;
            v1 = v1 > 0.f ? v1 : 0.f;
            v1 += bf2f(hr[(size_t)i * D_DIM + wbase + 16 + m]);
            gr[(size_t)i * D_DIM + wbase + 16 + m] = v1;
            sa1[i] += v1;
        }
    }

    float* ss = segsum + (size_t)seg * NCOL + (size_t)(rB + quad * 4) * D_DIM;
#pragma unroll
    for (int i = 0; i < 4; ++i) {
        ss[(size_t)i * D_DIM + wbase + m] = sa0[i];
        ss[(size_t)i * D_DIM + wbase + 16 + m] = sa1[i];
    }
}

// ---------------- K3: in-place exclusive prefix over segment sums ----------------
__global__ __launch_bounds__(256) void k3_prefix(float* __restrict__ segsum) {
    int col = blockIdx.x * 256 + threadIdx.x;   // 0 .. 32767
    float acc = 0.f;
#pragma unroll 4
    for (int j = 0; j < NSEG; ++j) {
        size_t idx = (size_t)j * NCOL + col;
        float v = segsum[idx];
        segsum[idx] = acc;
        acc += v;
    }
}

// ---------------- K4: apply prefix + within-segment running sum (float4) ----------------
__global__ __launch_bounds__(256) void k4_apply(float* __restrict__ g,
                                                const float* __restrict__ segsum) {
    int t = blockIdx.x * 256 + threadIdx.x;     // 0 .. NSEG*8192-1
    int c4 = (t & 8191) * 4;
    int seg = t >> 13;
    int s0 = seg * SEGLEN;
    int send = min(s0 + SEGLEN, SM1);

    f32x4 acc = *(const f32x4*)(segsum + (size_t)seg * NCOL + c4);
#pragma unroll 1
    for (int s = s0; s < send; ++s) {
        float* p = g + (size_t)s * NCOL + c4;
        f32x4 v = *(const f32x4*)p;
        acc += v;
        *(f32x4*)p = acc;
    }
}

extern "C" void kernel_launch(void* const* d_in, const int* in_sizes, int n_in,
                              void* d_out, int out_size, void* d_ws, size_t ws_size,
                              hipStream_t stream) {
    const float* src = (const float*)d_in[0];
    const float* Wm  = (const float*)d_in[1];
    const float* bm  = (const float*)d_in[2];
    const float* Wb  = (const float*)d_in[3];
    const float* bb  = (const float*)d_in[4];
    float* out = (float*)d_out;

    char* ws = (char*)d_ws;
    short* h       = (short*)(ws);
    float* segsum  = (float*)(ws + 134217728ull);
    short* Wm_sw   = (short*)(ws + 142606336ull);
    short* Wb_sw   = (short*)(ws + 142639104ull);

    hipLaunchKernelGGL(k0_prep, dim3(128), dim3(256), 0, stream, Wm, Wb, Wm_sw, Wb_sw);
    hipLaunchKernelGGL(k1_h, dim3((S_DIM * B_DIM) / (16 * K1_RT)), dim3(256), 0, stream,
                       src, Wm_sw, bm, h);
    hipLaunchKernelGGL(k2_fused, dim3(NSEG * 16), dim3(256), 0, stream,
                       h, Wb_sw, bb, out, segsum);
    hipLaunchKernelGGL(k3_prefix, dim3(NCOL / 256), dim3(256), 0, stream, segsum);
    hipLaunchKernelGGL(k4_apply, dim3((NSEG * (NCOL / 4)) / 256), dim3(256), 0, stream,
                       out, segsum);
}

// Round 3
// 786.026 us; speedup vs baseline: 1.0682x; 1.0199x over previous
//
#include <hip/hip_runtime.h>

// LieNet: h = relu(src@Wm+bm); tmp = relu(cat(h[s],h[s+1])@Wb+bb); out = cumsum_s(h[:-1]+tmp)
// S=2048, B=256, D=128. All fp32 in/out; internal GEMMs in bf16 MFMA (fp32 acc).
//
// Pipeline (g buffer ELIMINATED via recompute):
//   k0_prep      : swizzle Wm/Wb into MFMA B-fragment order (bf16)
//   k1_h         : h = relu(src@Wm+bm) -> bf16 (Wm frags reg-cached, 8 row-tiles/block)
//   k2_core<0>   : per (segment, row-tile): loop s computing g[s] in regs, accumulate
//                  per-segment column sums -> segsum (8 MB). No g write.
//   k3_prefix    : in-register exclusive prefix over the 64 segment sums per column.
//   k2_core<1>   : recompute g[s], running cumsum from prefix, write out directly.
//   k2 structure : 8 waves/block, each wave owns 16 cols (1 n-frag) of a 16-row tile.
//                  ALL Wb fragments (bw0+bw1) register-resident. A-fragments double-
//                  buffered with h[s+1]->h[s] reuse + mid-iteration prefetch of h[s+2].
//
// Workspace layout (~142.7 MB):
//   [0, 134217728)               h as bf16, [S=2048][B=256][D=128]
//   [134217728, 142606336)       segsum fp32, [NSEG=64][32768]
//   [142606336, 142639104)       Wm swizzled bf16 (16384 elems)
//   [142639104, 142704640)       Wb swizzled bf16 (32768 elems, two 128-halves)

#define S_DIM 2048
#define B_DIM 256
#define D_DIM 128
#define SM1   2047
#define NCOL  (B_DIM * D_DIM)   // 32768
#define NSEG  64
#define SEGLEN 32               // 64*32 = 2048 >= 2047

typedef __attribute__((ext_vector_type(8))) short bf16x8;
typedef __attribute__((ext_vector_type(4))) float f32x4;

__device__ inline short f2bf(float x) {
    unsigned u = __builtin_bit_cast(unsigned, x);
    unsigned r = (u + 0x7fffu + ((u >> 16) & 1u)) >> 16;
    return (short)r;
}
__device__ inline float bf2f(short v) {
    unsigned u = ((unsigned)(unsigned short)v) << 16;
    return __builtin_bit_cast(float, u);
}

// ---------------- K0: swizzle weights into MFMA B-fragment order ----------------
// B-fragment for mfma_f32_16x16x32_bf16: lane holds B[k=quad*8+j][n=(lane&15)],
// j=0..7. Swizzled index: ((n_tile*4 + kt)*64 + lane)*8 + j.
__global__ __launch_bounds__(256) void k0_prep(const float* __restrict__ Wm,
                                               const float* __restrict__ Wb,
                                               short* __restrict__ Wm_sw,
                                               short* __restrict__ Wb_sw) {
    int idx = blockIdx.x * 256 + threadIdx.x;
    if (idx < 16384) {
        int j = idx & 7, lane = (idx >> 3) & 63, kt = (idx >> 9) & 3, nt = idx >> 11;
        int k = kt * 32 + ((lane >> 4) << 3) + j;
        int n = nt * 16 + (lane & 15);
        Wm_sw[idx] = f2bf(Wm[k * D_DIM + n]);
    }
    if (idx < 32768) {
        int half = idx >> 14;
        int r = idx & 16383;
        int j = r & 7, lane = (r >> 3) & 63, kt = (r >> 9) & 3, nt = r >> 11;
        int k = kt * 32 + ((lane >> 4) << 3) + j;
        int n = nt * 16 + (lane & 15);
        Wb_sw[idx] = f2bf(Wb[(half * 128 + k) * D_DIM + n]);
    }
}

// ---------------- K1: h = relu(src @ Wm + bm), bf16 out ----------------
// Block = 4 waves, wave w owns cols [w*32, w*32+32). 8 row-tiles of 16 rows per block.
#define K1_RT 8
__global__ __launch_bounds__(256, 4) void k1_h(const float* __restrict__ src,
                                               const short* __restrict__ Wm_sw,
                                               const float* __restrict__ bm,
                                               short* __restrict__ h) {
    const int lane = threadIdx.x & 63;
    const int wave = threadIdx.x >> 6;
    const int m = lane & 15;
    const int quad = lane >> 4;
    const int wbase = wave * 32;
    const int n0 = wave * 2;

    bf16x8 bw[2][4];
#pragma unroll
    for (int n = 0; n < 2; ++n)
#pragma unroll
        for (int kt = 0; kt < 4; ++kt)
            bw[n][kt] = *(const bf16x8*)(Wm_sw + ((size_t)((n0 + n) * 4 + kt) * 64 + lane) * 8);

    const float bias0 = bm[wbase + m];
    const float bias1 = bm[wbase + 16 + m];

#pragma unroll 1
    for (int r = 0; r < K1_RT; ++r) {
        const int rowBase = blockIdx.x * (16 * K1_RT) + r * 16;
        const float* arow = src + (size_t)(rowBase + m) * D_DIM + quad * 8;

        bf16x8 a[4];
#pragma unroll
        for (int kt = 0; kt < 4; ++kt) {
            float4 lo = *(const float4*)(arow + kt * 32);
            float4 hi = *(const float4*)(arow + kt * 32 + 4);
            a[kt][0] = f2bf(lo.x); a[kt][1] = f2bf(lo.y);
            a[kt][2] = f2bf(lo.z); a[kt][3] = f2bf(lo.w);
            a[kt][4] = f2bf(hi.x); a[kt][5] = f2bf(hi.y);
            a[kt][6] = f2bf(hi.z); a[kt][7] = f2bf(hi.w);
        }

        f32x4 acc0 = (f32x4){0.f, 0.f, 0.f, 0.f};
        f32x4 acc1 = (f32x4){0.f, 0.f, 0.f, 0.f};
#pragma unroll
        for (int kt = 0; kt < 4; ++kt) {
            acc0 = __builtin_amdgcn_mfma_f32_16x16x32_bf16(a[kt], bw[0][kt], acc0, 0, 0, 0);
            acc1 = __builtin_amdgcn_mfma_f32_16x16x32_bf16(a[kt], bw[1][kt], acc1, 0, 0, 0);
        }

        short* hout = h + (size_t)(rowBase + quad * 4) * D_DIM;
#pragma unroll
        for (int i = 0; i < 4; ++i) {
            float v0 = acc0[i] + bias0;
            v0 = v0 > 0.f ? v0 : 0.f;
            hout[(size_t)i * D_DIM + wbase + m] = f2bf(v0);
            float v1 = acc1[i] + bias1;
            v1 = v1 > 0.f ? v1 : 0.f;
            hout[(size_t)i * D_DIM + wbase + 16 + m] = f2bf(v1);
        }
    }
}

// ---------------- K2 core: g recompute, segment sums / final cumsum ----------------
// Grid = NSEG * 16 row-tiles, 512 threads (8 waves). Wave w owns cols [w*16, w*16+16).
// WRITE_OUT=0: accumulate segment column sums -> segsum.
// WRITE_OUT=1: running cumsum seeded from segpre (exclusive prefix), write out.
template<bool WRITE_OUT>
__global__ __launch_bounds__(512, 4) void k2_core(const short* __restrict__ h,
                                                  const short* __restrict__ Wb_sw,
                                                  const float* __restrict__ bb,
                                                  const float* __restrict__ segpre,
                                                  float* __restrict__ segsum,
                                                  float* __restrict__ out) {
    const int lane = threadIdx.x & 63;
    const int n = threadIdx.x >> 6;       // wave = n-frag index, 0..7
    const int m = lane & 15;
    const int quad = lane >> 4;
    const int seg = blockIdx.x >> 4;
    const int rB = (blockIdx.x & 15) * 16;

    // All Wb fragments for this wave's 16 cols: register-resident.
    bf16x8 bw0[4], bw1[4];
#pragma unroll
    for (int kt = 0; kt < 4; ++kt) {
        bw0[kt] = *(const bf16x8*)(Wb_sw + ((size_t)(n * 4 + kt) * 64 + lane) * 8);
        bw1[kt] = *(const bf16x8*)(Wb_sw + 16384 + ((size_t)(n * 4 + kt) * 64 + lane) * 8);
    }
    const float bias = bb[n * 16 + m];

    const int s0 = seg * SEGLEN;
    const int send = min(s0 + SEGLEN, SM1);

    // running accumulator: WRITE_OUT ? cumsum seeded from prefix : segment sum
    f32x4 sacc;
    if (WRITE_OUT) {
        const float* sp = segpre + (size_t)seg * NCOL + (size_t)(rB + quad * 4) * D_DIM + n * 16 + m;
#pragma unroll
        for (int i = 0; i < 4; ++i) sacc[i] = sp[(size_t)i * D_DIM];
    } else {
        sacc = (f32x4){0.f, 0.f, 0.f, 0.f};
    }

    // A-fragment double buffer: A0 = h[s], A1 = h[s+1]
    bf16x8 A0[4], A1[4];
    {
        const short* p0 = h + ((size_t)s0 * B_DIM + rB + m) * D_DIM + quad * 8;
        const short* p1 = p0 + (size_t)B_DIM * D_DIM;
#pragma unroll
        for (int kt = 0; kt < 4; ++kt) { A0[kt] = *(const bf16x8*)(p0 + kt * 32); A1[kt] = *(const bf16x8*)(p1 + kt * 32); }
    }

#define K2_STEP(CUR, NXT, SS, PF)                                                              \
    {                                                                                          \
        const int s_ = (SS);                                                                   \
        f32x4 acc = (f32x4){0.f, 0.f, 0.f, 0.f};                                               \
        _Pragma("unroll")                                                                      \
        for (int kt = 0; kt < 4; ++kt)                                                         \
            acc = __builtin_amdgcn_mfma_f32_16x16x32_bf16(CUR[kt], bw0[kt], acc, 0, 0, 0);     \
        if (PF) {   /* CUR is dead now: prefetch h[s+2] into it */                             \
            const int sp_ = min(s_ + 2, SM1);                                                  \
            const short* pp = h + ((size_t)sp_ * B_DIM + rB + m) * D_DIM + quad * 8;           \
            _Pragma("unroll")                                                                  \
            for (int kt = 0; kt < 4; ++kt) CUR[kt] = *(const bf16x8*)(pp + kt * 32);           \
        }                                                                                      \
        _Pragma("unroll")                                                                      \
        for (int kt = 0; kt < 4; ++kt)                                                         \
            acc = __builtin_amdgcn_mfma_f32_16x16x32_bf16(NXT[kt], bw1[kt], acc, 0, 0, 0);     \
        const short* hr = h + ((size_t)s_ * B_DIM + rB + quad * 4) * D_DIM + n * 16 + m;       \
        float* orow = out + ((size_t)s_ * NCOL + (size_t)(rB + quad * 4) * D_DIM + n * 16 + m);\
        _Pragma("unroll")                                                                      \
        for (int i = 0; i < 4; ++i) {                                                          \
            float v = acc[i] + bias;                                                           \
            v = v > 0.f ? v : 0.f;                                                             \
            v += bf2f(hr[(size_t)i * D_DIM]);                                                  \
            sacc[i] += v;                                                                      \
            if (WRITE_OUT) orow[(size_t)i * D_DIM] = sacc[i];                                  \
        }                                                                                      \
    }

    int s = s0;
#pragma unroll 1
    for (; s + 2 <= send; s += 2) {
        K2_STEP(A0, A1, s, 1)
        K2_STEP(A1, A0, s + 1, 1)
    }
    if (s < send) {
        K2_STEP(A0, A1, s, 0)
    }
#undef K2_STEP

    if (!WRITE_OUT) {
        float* ss = segsum + (size_t)seg * NCOL + (size_t)(rB + quad * 4) * D_DIM + n * 16 + m;
#pragma unroll
        for (int i = 0; i < 4; ++i) ss[(size_t)i * D_DIM] = sacc[i];
    }
}

// ---------------- K3: in-place exclusive prefix over segment sums ----------------
// All 64 values loaded into registers (independent loads), then prefix, then store.
__global__ __launch_bounds__(256) void k3_prefix(float* __restrict__ segsum) {
    int col = blockIdx.x * 256 + threadIdx.x;   // 0 .. 32767
    float v[NSEG];
#pragma unroll
    for (int j = 0; j < NSEG; ++j) v[j] = segsum[(size_t)j * NCOL + col];
    float acc = 0.f;
#pragma unroll
    for (int j = 0; j < NSEG; ++j) {
        segsum[(size_t)j * NCOL + col] = acc;
        acc += v[j];
    }
}

extern "C" void kernel_launch(void* const* d_in, const int* in_sizes, int n_in,
                              void* d_out, int out_size, void* d_ws, size_t ws_size,
                              hipStream_t stream) {
    const float* src = (const float*)d_in[0];
    const float* Wm  = (const float*)d_in[1];
    const float* bm  = (const float*)d_in[2];
    const float* Wb  = (const float*)d_in[3];
    const float* bb  = (const float*)d_in[4];
    float* out = (float*)d_out;

    char* ws = (char*)d_ws;
    short* h       = (short*)(ws);
    float* segsum  = (float*)(ws + 134217728ull);
    short* Wm_sw   = (short*)(ws + 142606336ull);
    short* Wb_sw   = (short*)(ws + 142639104ull);

    hipLaunchKernelGGL(k0_prep, dim3(128), dim3(256), 0, stream, Wm, Wb, Wm_sw, Wb_sw);
    hipLaunchKernelGGL(k1_h, dim3((S_DIM * B_DIM) / (16 * K1_RT)), dim3(256), 0, stream,
                       src, Wm_sw, bm, h);
    hipLaunchKernelGGL((k2_core<false>), dim3(NSEG * 16), dim3(512), 0, stream,
                       h, Wb_sw, bb, (const float*)nullptr, segsum, out);
    hipLaunchKernelGGL(k3_prefix, dim3(NCOL / 256), dim3(256), 0, stream, segsum);
    hipLaunchKernelGGL((k2_core<true>), dim3(NSEG * 16), dim3(512), 0, stream,
                       h, Wb_sw, bb, (const float*)segsum, (float*)nullptr, out);
}